// Round 3
// baseline (465.574 us; speedup 1.0000x reference)
//
#include <hip/hip_runtime.h>

#define NB 32
#define NC 512
#define NH 56
#define NW 56
#define HW 3136       // 56*56
#define CHW 1605632   // 512*3136
#define CCH 64        // channels per LDS chunk in k2a
#define LSTR 60       // LDS row stride in floats (240 B, 16B-aligned)

// ---------------- K1: per-(b,c) mean/max of relu(x) -> mask ----------------
__global__ __launch_bounds__(256) void k1_mask(const float* __restrict__ x,
                                               float* __restrict__ mask) {
    const int plane = blockIdx.x;  // b*512 + c
    const float4* px = (const float4*)(x + (size_t)plane * HW);
    float lmax = 0.f;
    double lsum = 0.0;
    for (int i = threadIdx.x; i < HW / 4; i += 256) {
        float4 v = px[i];
        float f0 = fmaxf(v.x, 0.f), f1 = fmaxf(v.y, 0.f);
        float f2 = fmaxf(v.z, 0.f), f3 = fmaxf(v.w, 0.f);
        lmax = fmaxf(lmax, fmaxf(fmaxf(f0, f1), fmaxf(f2, f3)));
        lsum += (double)f0 + (double)f1 + (double)f2 + (double)f3;
    }
    for (int off = 32; off; off >>= 1) {
        lsum += __shfl_xor(lsum, off);
        lmax = fmaxf(lmax, __shfl_xor(lmax, off));
    }
    __shared__ double ssum[4];
    __shared__ float smax[4];
    int wid = threadIdx.x >> 6, lane = threadIdx.x & 63;
    if (lane == 0) { ssum[wid] = lsum; smax[wid] = lmax; }
    __syncthreads();
    if (threadIdx.x == 0) {
        double s = ssum[0] + ssum[1] + ssum[2] + ssum[3];
        float m = fmaxf(fmaxf(smax[0], smax[1]), fmaxf(smax[2], smax[3]));
        float avg = (float)(s / 3136.0);
        mask[plane] = ((m - avg) < 0.5f) ? 0.f : 1.f;
    }
}

// -------- K2a: per-(b,h): channel max/mean over chunked LDS -> bb --------
__global__ __launch_bounds__(256) void k2a_bb(const float* __restrict__ x,
                                              const float* __restrict__ mask,
                                              float* __restrict__ bb) {
    const int bh = blockIdx.x;
    const int b = bh / NH, h = bh % NH;
    __shared__ float lds[CCH * LSTR];            // 15360 B
    __shared__ float sm[4][NW];                  // 896 B
    __shared__ double ss[4][NW];                 // 1792 B
    const int tid = threadIdx.x;
    const size_t base = (size_t)b * CHW + (size_t)h * NW;
    const int w = tid % NW, q = tid / NW;        // roles valid for tid < 224
    float cmax = 0.f;
    double csum = 0.0;
    for (int c0 = 0; c0 < NC; c0 += CCH) {
        for (int i = tid; i < CCH * 14; i += 256) {
            int cl = i / 14, w4 = (i % 14) * 4;
            float4 v = *(const float4*)(x + base + (size_t)(c0 + cl) * HW + w4);
            float mk = mask[b * NC + c0 + cl];   // 0.0 or 1.0 (mul by 1.0 exact)
            v.x = fmaxf(v.x, 0.f) * mk;
            v.y = fmaxf(v.y, 0.f) * mk;
            v.z = fmaxf(v.z, 0.f) * mk;
            v.w = fmaxf(v.w, 0.f) * mk;
            *(float4*)(&lds[cl * LSTR + w4]) = v;
        }
        __syncthreads();
        if (tid < 224) {
#pragma unroll
            for (int i = 0; i < CCH / 4; i++) {
                float f = lds[(q + 4 * i) * LSTR + w];
                cmax = fmaxf(cmax, f);
                csum += (double)f;
            }
        }
        __syncthreads();
    }
    if (tid < 224) { sm[q][w] = cmax; ss[q][w] = csum; }
    __syncthreads();
    if (tid < NW) {
        float m = fmaxf(fmaxf(sm[0][tid], sm[1][tid]), fmaxf(sm[2][tid], sm[3][tid]));
        double s = ss[0][tid] + ss[1][tid] + ss[2][tid] + ss[3][tid];
        double cmean = s * (1.0 / 512.0);
        double d = fabs((double)m - cmean);
        bb[(size_t)b * HW + h * NW + tid] = (float)(1.0 - exp(-d));
    }
}

// ---- K2b: per-(b,c) plane: x_max and pooled of x2 = bb*x1 (one block) ----
__global__ __launch_bounds__(256) void k2b_stats(const float* __restrict__ x,
                                                 const float* __restrict__ mask,
                                                 const float* __restrict__ bb,
                                                 float* __restrict__ xmax,
                                                 float* __restrict__ pooled) {
    const int plane = blockIdx.x;  // b*512 + c
    const int b = plane >> 9;
    const float4* px = (const float4*)(x + (size_t)plane * HW);
    const float4* pbb = (const float4*)(bb + (size_t)b * HW);
    const float mk = mask[plane];
    float m = 0.f;
    double s = 0.0;
    for (int i = threadIdx.x; i < HW / 4; i += 256) {
        float4 v = px[i];
        float4 bv = pbb[i];
        float x0 = fmaxf(v.x, 0.f) * mk * bv.x;  // identical fp32 chain as K4
        float x1 = fmaxf(v.y, 0.f) * mk * bv.y;
        float x2 = fmaxf(v.z, 0.f) * mk * bv.z;
        float x3 = fmaxf(v.w, 0.f) * mk * bv.w;
        m = fmaxf(m, fmaxf(fmaxf(x0, x1), fmaxf(x2, x3)));
        s += (double)x0 + (double)x1 + (double)x2 + (double)x3;
    }
    for (int off = 32; off; off >>= 1) {
        s += __shfl_xor(s, off);
        m = fmaxf(m, __shfl_xor(m, off));
    }
    __shared__ double ssum[4];
    __shared__ float smax[4];
    int wid = threadIdx.x >> 6, lane = threadIdx.x & 63;
    if (lane == 0) { ssum[wid] = s; smax[wid] = m; }
    __syncthreads();
    if (threadIdx.x == 0) {
        double st = ssum[0] + ssum[1] + ssum[2] + ssum[3];
        float mt = fmaxf(fmaxf(smax[0], smax[1]), fmaxf(smax[2], smax[3]));
        xmax[plane] = mt;
        pooled[plane] = (float)(st / 3136.0);
    }
}

// ------------- K3: FC gates (wave-per-output dot products) -> thres -------------
__global__ __launch_bounds__(256) void k3_gates(const float* __restrict__ pooled,
                                                const float* __restrict__ W1,
                                                const float* __restrict__ W3,
                                                const float* __restrict__ xmax,
                                                float* __restrict__ thres) {
    int wave = threadIdx.x >> 6, lane = threadIdx.x & 63;
    int task0 = (blockIdx.x * 4 + wave) * 4;
    for (int t = 0; t < 4; t++) {
        int task = task0 + t;                       // b*512 + j
        int b = task >> 9, j = task & 511;
        const float* r1 = W1 + j * 512;
        const float* r3 = W3 + j * 512;
        const float* pr = pooled + b * 512;
        double s1 = 0.0, s3 = 0.0;
        for (int k = lane; k < 512; k += 64) {
            double p = (double)pr[k];
            s1 += p * (double)r1[k];
            s3 += p * (double)r3[k];
        }
        for (int off = 32; off; off >>= 1) {
            s1 += __shfl_xor(s1, off);
            s3 += __shfl_xor(s3, off);
        }
        if (lane == 0) {
            float c1 = (float)(1.0 / (1.0 + exp(-s1)));   // sigmoid
            double r = s3 > 0.0 ? s3 : 0.0;               // relu
            float c3 = (float)((r < 1.0) ? 1.2 : r);
            thres[task] = c1 * c3 * xmax[task];           // np's fp32 mul order
        }
    }
}

// ---------------- K4: recompute x2, threshold, write fp32 out ----------------
__global__ __launch_bounds__(256) void k4_out(const float* __restrict__ x,
                                              const float* __restrict__ mask,
                                              const float* __restrict__ bb,
                                              const float* __restrict__ thres,
                                              float* __restrict__ out) {
    const int plane = blockIdx.x;
    const int b = plane >> 9;
    const float4* px = (const float4*)(x + (size_t)plane * HW);
    float4* po = (float4*)(out + (size_t)plane * HW);
    const float4* pbb = (const float4*)(bb + (size_t)b * HW);
    const float th = thres[plane];
    const float mk = mask[plane];
    for (int i = threadIdx.x; i < HW / 4; i += 256) {
        float4 v = px[i];
        float4 bv = pbb[i];
        float x0 = fmaxf(v.x, 0.f) * mk * bv.x;  // identical fp32 chain as K2b
        float x1 = fmaxf(v.y, 0.f) * mk * bv.y;
        float x2 = fmaxf(v.z, 0.f) * mk * bv.z;
        float x3 = fmaxf(v.w, 0.f) * mk * bv.w;
        float4 o;
        o.x = (x0 < th) ? 0.f : x0;
        o.y = (x1 < th) ? 0.f : x1;
        o.z = (x2 < th) ? 0.f : x2;
        o.w = (x3 < th) ? 0.f : x3;
        po[i] = o;
    }
}

extern "C" void kernel_launch(void* const* d_in, const int* in_sizes, int n_in,
                              void* d_out, int out_size, void* d_ws, size_t ws_size,
                              hipStream_t stream) {
    const float* x  = (const float*)d_in[0];
    const float* W1 = (const float*)d_in[1];
    const float* W3 = (const float*)d_in[2];
    float* out = (float*)d_out;
    float* ws = (float*)d_ws;
    // workspace layout (floats): total 165,888 floats = 648 KB
    float* mask   = ws;            // 16384
    float* bb     = ws + 16384;    // 100352
    float* xmax   = ws + 116736;   // 16384
    float* pooled = ws + 133120;   // 16384
    float* thres  = ws + 149504;   // 16384

    hipLaunchKernelGGL(k1_mask,    dim3(NB * NC), dim3(256), 0, stream, x, mask);
    hipLaunchKernelGGL(k2a_bb,     dim3(NB * NH), dim3(256), 0, stream, x, mask, bb);
    hipLaunchKernelGGL(k2b_stats,  dim3(NB * NC), dim3(256), 0, stream, x, mask, bb, xmax, pooled);
    hipLaunchKernelGGL(k3_gates,   dim3(1024),    dim3(256), 0, stream, pooled, W1, W3, xmax, thres);
    hipLaunchKernelGGL(k4_out,     dim3(NB * NC), dim3(256), 0, stream, x, mask, bb, thres, out);
}